// Round 1
// baseline (356.740 us; speedup 1.0000x reference)
//
#include <hip/hip_runtime.h>
#include <cstddef>

#define NB 4
#define NC 256
#define ND 128
#define NH 128
#define NW 128
#define NHW (NH*NW)
#define NT 16384

// Kernel 1: vm[b][p][d] = sum_c fmap[b][c][p] * Wp[d][c]   (channel-last output)
// Extra grid row (blockIdx.y == NB) transposes W1 -> W1T for scalar-load MLP.
__global__ __launch_bounds__(256, 4)
void proj_kernel(const float* __restrict__ fmap, const float* __restrict__ Wp,
                 const float* __restrict__ W1, float* __restrict__ vm,
                 float* __restrict__ W1T)
{
    if (blockIdx.y == NB) {
        if (blockIdx.x == 0) {
            for (int i = threadIdx.x; i < ND*ND; i += 256) {
                int e = i >> 7, d = i & 127;
                W1T[d*ND + e] = W1[e*ND + d];
            }
        }
        return;
    }
    const int b  = blockIdx.y;
    const int p0 = blockIdx.x * 64;
    __shared__ float As[16][64];    // [cc][p]
    __shared__ float Ws[16][128];   // [cc][d]
    const int t  = threadIdx.x;
    const int pp = (t >> 4) * 4;    // 4 pixels per thread
    const int d0 = (t & 15) * 8;    // 8 channels per thread

    float acc[4][8];
    #pragma unroll
    for (int i = 0; i < 4; ++i)
        #pragma unroll
        for (int j = 0; j < 8; ++j) acc[i][j] = 0.f;

    const int cc_a = t >> 4;          // staging: fmap tile row
    const int px_a = (t & 15) * 4;    // staging: fmap tile col (float4)
    const int d_w  = t >> 1;          // staging: Wp row
    const int q_w  = (t & 1) * 8;     // staging: Wp col offset

    for (int c0 = 0; c0 < NC; c0 += 16) {
        float4 fa = *(const float4*)&fmap[((size_t)(b*NC + c0 + cc_a))*NHW + p0 + px_a];
        float4 wa = *(const float4*)&Wp[(size_t)d_w*NC + c0 + q_w];
        float4 wb = *(const float4*)&Wp[(size_t)d_w*NC + c0 + q_w + 4];
        *(float4*)&As[cc_a][px_a] = fa;
        Ws[q_w+0][d_w] = wa.x; Ws[q_w+1][d_w] = wa.y;
        Ws[q_w+2][d_w] = wa.z; Ws[q_w+3][d_w] = wa.w;
        Ws[q_w+4][d_w] = wb.x; Ws[q_w+5][d_w] = wb.y;
        Ws[q_w+6][d_w] = wb.z; Ws[q_w+7][d_w] = wb.w;
        __syncthreads();
        #pragma unroll
        for (int cc = 0; cc < 16; ++cc) {
            float4 a4  = *(const float4*)&As[cc][pp];
            float4 b40 = *(const float4*)&Ws[cc][d0];
            float4 b41 = *(const float4*)&Ws[cc][d0+4];
            const float av[4] = {a4.x, a4.y, a4.z, a4.w};
            const float bv[8] = {b40.x,b40.y,b40.z,b40.w,b41.x,b41.y,b41.z,b41.w};
            #pragma unroll
            for (int i = 0; i < 4; ++i)
                #pragma unroll
                for (int j = 0; j < 8; ++j)
                    acc[i][j] = fmaf(av[i], bv[j], acc[i][j]);
        }
        __syncthreads();
    }
    #pragma unroll
    for (int i = 0; i < 4; ++i) {
        size_t base = ((size_t)b*NHW + p0 + pp + i) * ND + d0;
        *(float4*)&vm[base]   = make_float4(acc[i][0],acc[i][1],acc[i][2],acc[i][3]);
        *(float4*)&vm[base+4] = make_float4(acc[i][4],acc[i][5],acc[i][6],acc[i][7]);
    }
}

// Kernel 2: fused 4x4 separable gather (== mean of 9 bilinear samples) + 2-layer MLP.
// 64 points/block, 256 threads. feat tile in LDS (stride 132 keeps float4 alignment).
__global__ __launch_bounds__(256, 4)
void gather_mlp(const float* __restrict__ vm, const float* __restrict__ coords,
                const float* __restrict__ W1T, const float* __restrict__ b1,
                const float* __restrict__ W2, const float* __restrict__ b2,
                float* __restrict__ out)
{
    __shared__ float feat[64][132];
    __shared__ float part[64][8];
    const int t  = threadIdx.x;
    const int g0 = blockIdx.x * 64;
    const int b  = g0 / NT;   // uniform per block (256 blocks per batch)

    // ---- Phase A: gather. 4 threads per point, 32 channels each. ----
    {
        const int pt = t >> 2;
        const int c4 = t & 3;
        const int g  = g0 + pt;
        const float cx = coords[(size_t)g*2 + 0];
        const float cy = coords[(size_t)g*2 + 1];
        // align_corners=True: ix for offset bx is exactly cx*(W-1) + bx
        const float ix = cx * (float)(NW - 1);
        const float iy = cy * (float)(NH - 1);
        const float x0f = floorf(ix), y0f = floorf(iy);
        const int x0 = (int)x0f, y0 = (int)y0f;
        const float wx1 = ix - x0f, wy1 = iy - y0f;
        const float wxv[4] = {1.f - wx1, 1.f, 1.f, wx1};
        const float wyv[4] = {1.f - wy1, 1.f, 1.f, wy1};
        float acc[32];
        #pragma unroll
        for (int k = 0; k < 32; ++k) acc[k] = 0.f;
        const float* vmb = vm + (size_t)b*NHW*ND + c4*32;
        #pragma unroll
        for (int j = 0; j < 4; ++j) {
            const int Y  = y0 - 1 + j;
            const int Yc = min(max(Y, 0), NH-1);
            const bool vy = (Y >= 0) & (Y < NH);
            #pragma unroll
            for (int i = 0; i < 4; ++i) {
                const int X  = x0 - 1 + i;
                const int Xc = min(max(X, 0), NW-1);
                const bool vx = (X >= 0) & (X < NW);
                const float w = (vx & vy) ? wxv[i]*wyv[j] : 0.f;  // zeros padding
                const float* src = vmb + (size_t)(Yc*NW + Xc)*ND;
                #pragma unroll
                for (int q = 0; q < 8; ++q) {
                    float4 v = *(const float4*)&src[q*4];
                    acc[q*4+0] = fmaf(w, v.x, acc[q*4+0]);
                    acc[q*4+1] = fmaf(w, v.y, acc[q*4+1]);
                    acc[q*4+2] = fmaf(w, v.z, acc[q*4+2]);
                    acc[q*4+3] = fmaf(w, v.w, acc[q*4+3]);
                }
            }
        }
        const float s = 1.f/9.f;
        #pragma unroll
        for (int q = 0; q < 8; ++q)
            *(float4*)&feat[pt][c4*32 + q*4] =
                make_float4(acc[q*4]*s, acc[q*4+1]*s, acc[q*4+2]*s, acc[q*4+3]*s);
    }
    __syncthreads();

    // ---- Phase B: layer 1 (+layer-2 partials). thread = (point, 32-wide e-block) ----
    {
        const int pt = t & 63;
        const int eb = t >> 6;
        const int e0 = __builtin_amdgcn_readfirstlane(eb * 32);  // wave-uniform -> s_load
        float acc[32];
        #pragma unroll
        for (int k = 0; k < 32; ++k) acc[k] = b1[e0 + k];
        #pragma unroll 2
        for (int d = 0; d < ND; d += 4) {
            float4 f = *(const float4*)&feat[pt][d];
            const float fv[4] = {f.x, f.y, f.z, f.w};
            #pragma unroll
            for (int jj = 0; jj < 4; ++jj) {
                const float* wrow = W1T + (size_t)(d + jj)*ND + e0;
                #pragma unroll
                for (int k = 0; k < 32; ++k)
                    acc[k] = fmaf(fv[jj], wrow[k], acc[k]);
            }
        }
        float s0 = 0.f, s1 = 0.f;
        const float* w20 = W2 + e0;
        const float* w21 = W2 + ND + e0;
        #pragma unroll
        for (int k = 0; k < 32; ++k) {
            float h = fmaxf(acc[k], 0.f);
            s0 = fmaf(h, w20[k], s0);
            s1 = fmaf(h, w21[k], s1);
        }
        part[pt][eb*2 + 0] = s0;
        part[pt][eb*2 + 1] = s1;
    }
    __syncthreads();

    // ---- Phase C: reduce 4 e-blocks, tanh, write ----
    if (t < 64) {
        const int g = g0 + t;
        float s0 = part[t][0] + part[t][2] + part[t][4] + part[t][6];
        float s1 = part[t][1] + part[t][3] + part[t][5] + part[t][7];
        const float cx = coords[(size_t)g*2 + 0];
        const float cy = coords[(size_t)g*2 + 1];
        const float MD = 0.5f / 512.0f;
        float2 o = make_float2(cx + tanhf(s0 + b2[0]) * MD,
                               cy + tanhf(s1 + b2[1]) * MD);
        *(float2*)&out[(size_t)g*2] = o;
    }
}

extern "C" void kernel_launch(void* const* d_in, const int* in_sizes, int n_in,
                              void* d_out, int out_size, void* d_ws, size_t ws_size,
                              hipStream_t stream)
{
    const float* fmap   = (const float*)d_in[0];
    const float* coords = (const float*)d_in[1];
    const float* Wp     = (const float*)d_in[2];
    const float* W1     = (const float*)d_in[3];
    const float* b1     = (const float*)d_in[4];
    const float* W2     = (const float*)d_in[5];
    const float* b2     = (const float*)d_in[6];
    float* out = (float*)d_out;

    float* vm  = (float*)d_ws;                    // (B,HW,D) fp32: 32 MB
    float* W1T = vm + (size_t)NB*NHW*ND;          // 128x128 fp32: 64 KB

    dim3 g1(NHW/64, NB + 1);                      // +1 row: W1 transpose
    proj_kernel<<<g1, 256, 0, stream>>>(fmap, Wp, W1, vm, W1T);
    dim3 g2((NB*NT)/64);
    gather_mlp<<<g2, 256, 0, stream>>>(vm, coords, W1T, b1, W2, b2, out);
}

// Round 2
// 321.111 us; speedup vs baseline: 1.1110x; 1.1110x over previous
//
#include <hip/hip_runtime.h>
#include <cstddef>

#define NB 4
#define NC 256
#define ND 128
#define NH 128
#define NW 128
#define NHW (NH*NW)
#define NT 16384
#define BSP 40   // Bs row stride in bf16 units: 80 B (16B-aligned reads, 2-way-max bank spread)

typedef short   short8  __attribute__((ext_vector_type(8)));
typedef unsigned short ushort8 __attribute__((ext_vector_type(8)));
typedef float   floatx4 __attribute__((ext_vector_type(4)));

// RNE fp32->bf16 pack of two floats into one dword (low ushort = first arg)
__device__ __forceinline__ unsigned pk_bf16(float a, float b) {
    unsigned ua = __float_as_uint(a);
    unsigned ub = __float_as_uint(b);
    ua += 0x7fffu + ((ua >> 16) & 1u);
    ub += 0x7fffu + ((ub >> 16) & 1u);
    return (ua >> 16) | (ub & 0xffff0000u);
}

__device__ __forceinline__ float bf2f(unsigned short u) {
    return __uint_as_float(((unsigned)u) << 16);
}

// Kernel 1: vm[b][p][d] = sum_c fmap[b][c][p] * Wp[d][c], output bf16 channel-last.
// MFMA bf16 16x16x32: M=d(128), N=p(64/block), K=c(256 in 8 chunks of 32).
// A (Wp) loaded fp32 from global (L2-resident 128KB), packed in-register.
// B (fmap chunk) transposed into LDS Bs[p][c] during staging.
// blockIdx.y == NB row: W1 -> W1T transpose for the MLP's scalar-load path.
__global__ __launch_bounds__(256, 4)
void proj_kernel(const float* __restrict__ fmap, const float* __restrict__ Wp,
                 const float* __restrict__ W1, unsigned short* __restrict__ vm,
                 float* __restrict__ W1T)
{
    if (blockIdx.y == NB) {
        if (blockIdx.x == 0)
            for (int i = threadIdx.x; i < ND*ND; i += 256)
                W1T[(i & 127)*ND + (i >> 7)] = W1[i];   // W1T[d][e] = W1[e][d]
        return;
    }
    const int b  = blockIdx.y;
    const int p0 = blockIdx.x * 64;
    __shared__ unsigned short Bs[64 * BSP];

    const int t    = threadIdx.x;
    const int lane = t & 63;
    const int w    = t >> 6;       // wave id: d-range w*32 .. w*32+32
    const int l15  = lane & 15;
    const int q    = lane >> 4;
    const int cK   = q * 8;        // k-offset within K=32 chunk for A/B fragments
    // staging: thread covers pixel pp, 8 channels starting at chs*8 (2 packs of 4)
    const int pp   = t & 63;
    const int chs  = t >> 6;

    floatx4 acc[2][4];
    #pragma unroll
    for (int i = 0; i < 2; ++i)
        #pragma unroll
        for (int j = 0; j < 4; ++j) acc[i][j] = (floatx4)(0.f);

    const float* fb = fmap + (size_t)b*NC*NHW + p0;

    for (int c0 = 0; c0 < NC; c0 += 32) {
        // ---- stage fmap[c0..c0+32)[p0..p0+64) transposed -> Bs[p][c] bf16 ----
        #pragma unroll
        for (int i = 0; i < 2; ++i) {
            const int cl = chs*8 + i*4;
            const float* s = fb + (size_t)(c0 + cl)*NHW + pp;
            float f0 = s[0], f1 = s[NHW], f2 = s[2*NHW], f3 = s[3*NHW];
            uint2 pk = make_uint2(pk_bf16(f0, f1), pk_bf16(f2, f3));
            *(uint2*)&Bs[pp*BSP + cl] = pk;   // byte addr pp*80 + cl*2: 8B-aligned
        }
        __syncthreads();
        // ---- A fragments from Wp (fp32 global, cast to bf16) ----
        short8 afr[2];
        #pragma unroll
        for (int dt = 0; dt < 2; ++dt) {
            const int d = w*32 + dt*16 + l15;
            const float* wr = Wp + (size_t)d*NC + c0 + cK;
            float4 g0 = *(const float4*)wr;
            float4 g1 = *(const float4*)(wr + 4);
            union { short8 v; unsigned u[4]; } cv;
            cv.u[0] = pk_bf16(g0.x, g0.y); cv.u[1] = pk_bf16(g0.z, g0.w);
            cv.u[2] = pk_bf16(g1.x, g1.y); cv.u[3] = pk_bf16(g1.z, g1.w);
            afr[dt] = cv.v;
        }
        // ---- MFMA: 2 d-tiles x 4 p-tiles ----
        #pragma unroll
        for (int pt = 0; pt < 4; ++pt) {
            short8 bfr = *(const short8*)&Bs[(pt*16 + l15)*BSP + cK]; // 16B-aligned
            acc[0][pt] = __builtin_amdgcn_mfma_f32_16x16x32_bf16(afr[0], bfr, acc[0][pt], 0, 0, 0);
            acc[1][pt] = __builtin_amdgcn_mfma_f32_16x16x32_bf16(afr[1], bfr, acc[1][pt], 0, 0, 0);
        }
        __syncthreads();
    }
    // ---- epilogue: C row=(q*4+reg) -> d, col=l15 -> p; 4 consecutive d per lane ----
    #pragma unroll
    for (int dt = 0; dt < 2; ++dt)
        #pragma unroll
        for (int pt = 0; pt < 4; ++pt) {
            const int p = p0 + pt*16 + l15;
            const int d = w*32 + dt*16 + q*4;
            floatx4 v = acc[dt][pt];
            uint2 pk = make_uint2(pk_bf16(v[0], v[1]), pk_bf16(v[2], v[3]));
            *(uint2*)&vm[((size_t)(b*NHW + p))*ND + d] = pk;  // 8B-aligned
        }
}

// Kernel 2: fused 4x4 separable gather (== mean of 9 bilinear samples, bf16 vm)
// + 2-layer MLP. 64 points/block, 256 threads, bf16 feat tile in LDS.
__global__ __launch_bounds__(256, 8)
void gather_mlp(const unsigned short* __restrict__ vm, const float* __restrict__ coords,
                const float* __restrict__ W1T, const float* __restrict__ b1,
                const float* __restrict__ W2, const float* __restrict__ b2,
                float* __restrict__ out)
{
    __shared__ unsigned short feat[64 * 136];  // row stride 272 B (17*16: aligned, odd*16 bank spread)
    __shared__ float part[64][8];
    const int t  = threadIdx.x;
    const int g0 = blockIdx.x * 64;
    const int b  = g0 / NT;   // uniform per block

    // ---- Phase A: gather. 4 threads per point, 32 bf16 channels each. ----
    {
        const int pt = t >> 2;
        const int c4 = t & 3;
        const int g  = g0 + pt;
        const float cx = coords[(size_t)g*2 + 0];
        const float cy = coords[(size_t)g*2 + 1];
        const float ix = cx * (float)(NW - 1);
        const float iy = cy * (float)(NH - 1);
        const float x0f = floorf(ix), y0f = floorf(iy);
        const int x0 = (int)x0f, y0 = (int)y0f;
        const float wx1 = ix - x0f, wy1 = iy - y0f;
        const float wxv[4] = {1.f - wx1, 1.f, 1.f, wx1};
        const float wyv[4] = {1.f - wy1, 1.f, 1.f, wy1};
        float acc[32];
        #pragma unroll
        for (int k = 0; k < 32; ++k) acc[k] = 0.f;
        const unsigned short* vmb = vm + (size_t)b*NHW*ND + c4*32;
        #pragma unroll
        for (int j = 0; j < 4; ++j) {
            const int Y  = y0 - 1 + j;
            const int Yc = min(max(Y, 0), NH-1);
            const bool vy = (Y >= 0) & (Y < NH);
            #pragma unroll
            for (int i = 0; i < 4; ++i) {
                const int X  = x0 - 1 + i;
                const int Xc = min(max(X, 0), NW-1);
                const bool vx = (X >= 0) & (X < NW);
                const float wgt = (vx & vy) ? wxv[i]*wyv[j] : 0.f;  // zeros padding
                const unsigned short* src = vmb + (size_t)(Yc*NW + Xc)*ND;
                #pragma unroll
                for (int qd = 0; qd < 4; ++qd) {
                    ushort8 u = *(const ushort8*)&src[qd*8];   // 16B load
                    #pragma unroll
                    for (int k = 0; k < 8; ++k)
                        acc[qd*8 + k] = fmaf(wgt, bf2f(u[k]), acc[qd*8 + k]);
                }
            }
        }
        const float s = 1.f/9.f;
        unsigned pk[16];
        #pragma unroll
        for (int k = 0; k < 16; ++k)
            pk[k] = pk_bf16(acc[2*k]*s, acc[2*k+1]*s);
        #pragma unroll
        for (int i = 0; i < 4; ++i)
            *(uint4*)&feat[pt*136 + c4*32 + i*8] =
                make_uint4(pk[4*i], pk[4*i+1], pk[4*i+2], pk[4*i+3]);
    }
    __syncthreads();

    // ---- Phase B: layer 1 (+layer-2 partials). thread = (point, 32-wide e-block) ----
    {
        const int pt = t & 63;
        const int eb = t >> 6;
        const int e0 = __builtin_amdgcn_readfirstlane(eb * 32);  // wave-uniform -> s_load
        float acc[32];
        #pragma unroll
        for (int k = 0; k < 32; ++k) acc[k] = b1[e0 + k];
        #pragma unroll 2
        for (int d = 0; d < ND; d += 8) {
            ushort8 u = *(const ushort8*)&feat[pt*136 + d];
            float fv[8];
            #pragma unroll
            for (int jj = 0; jj < 8; ++jj) fv[jj] = bf2f(u[jj]);
            #pragma unroll
            for (int jj = 0; jj < 8; ++jj) {
                const float* wrow = W1T + (size_t)(d + jj)*ND + e0;
                #pragma unroll
                for (int k = 0; k < 32; ++k)
                    acc[k] = fmaf(fv[jj], wrow[k], acc[k]);
            }
        }
        float s0 = 0.f, s1 = 0.f;
        const float* w20 = W2 + e0;
        const float* w21 = W2 + ND + e0;
        #pragma unroll
        for (int k = 0; k < 32; ++k) {
            float h = fmaxf(acc[k], 0.f);
            s0 = fmaf(h, w20[k], s0);
            s1 = fmaf(h, w21[k], s1);
        }
        part[pt][eb*2 + 0] = s0;
        part[pt][eb*2 + 1] = s1;
    }
    __syncthreads();

    // ---- Phase C: reduce 4 e-blocks, tanh, write ----
    if (t < 64) {
        const int g = g0 + t;
        float s0 = part[t][0] + part[t][2] + part[t][4] + part[t][6];
        float s1 = part[t][1] + part[t][3] + part[t][5] + part[t][7];
        const float cx = coords[(size_t)g*2 + 0];
        const float cy = coords[(size_t)g*2 + 1];
        const float MD = 0.5f / 512.0f;
        float2 o = make_float2(cx + tanhf(s0 + b2[0]) * MD,
                               cy + tanhf(s1 + b2[1]) * MD);
        *(float2*)&out[(size_t)g*2] = o;
    }
}

extern "C" void kernel_launch(void* const* d_in, const int* in_sizes, int n_in,
                              void* d_out, int out_size, void* d_ws, size_t ws_size,
                              hipStream_t stream)
{
    const float* fmap   = (const float*)d_in[0];
    const float* coords = (const float*)d_in[1];
    const float* Wp     = (const float*)d_in[2];
    const float* W1     = (const float*)d_in[3];
    const float* b1     = (const float*)d_in[4];
    const float* W2     = (const float*)d_in[5];
    const float* b2     = (const float*)d_in[6];
    float* out = (float*)d_out;

    unsigned short* vm = (unsigned short*)d_ws;                 // (B,HW,D) bf16: 16 MB
    float* W1T = (float*)((char*)d_ws + (size_t)NB*NHW*ND*2);   // 128x128 fp32: 64 KB

    dim3 g1(NHW/64, NB + 1);                                    // +1 row: W1 transpose
    proj_kernel<<<g1, 256, 0, stream>>>(fmap, Wp, W1, vm, W1T);
    dim3 g2((NB*NT)/64);
    gather_mlp<<<g2, 256, 0, stream>>>(vm, coords, W1T, b1, W2, b2, out);
}

// Round 3
// 207.672 us; speedup vs baseline: 1.7178x; 1.5462x over previous
//
#include <hip/hip_runtime.h>
#include <cstddef>

#define NB 4
#define NC 256
#define ND 128
#define NH 128
#define NW 128
#define NHW (NH*NW)
#define NT 16384

typedef short   short8  __attribute__((ext_vector_type(8)));
typedef unsigned short ushort8 __attribute__((ext_vector_type(8)));
typedef float   floatx4 __attribute__((ext_vector_type(4)));
typedef float   floatx2 __attribute__((ext_vector_type(2)));

// RNE fp32->bf16 pack of two floats into one dword (low ushort = first arg)
__device__ __forceinline__ unsigned pk_bf16(float a, float b) {
    unsigned ua = __float_as_uint(a);
    unsigned ub = __float_as_uint(b);
    ua += 0x7fffu + ((ua >> 16) & 1u);
    ub += 0x7fffu + ((ub >> 16) & 1u);
    return (ua >> 16) | (ub & 0xffff0000u);
}

__device__ __forceinline__ float bf2f(unsigned short u) {
    return __uint_as_float(((unsigned)u) << 16);
}

// Kernel 1: vm[b][p][d] = sum_c fmap[b][c][p] * Wp[d][c], bf16 channel-last.
// NO LDS, NO BARRIERS: each wave owns 16 pixels x all 128 d. B-fragments
// (pixels x channels) are built from 8 strided global dwords (4x64B coalesced
// segments per load); A-fragments from Wp fp32 rows (L1/L2-hot), packed
// in-register. Removes the stage->barrier HBM-latency serialization that held
// both previous proj variants at ~143us.
// Block bi<1024: GEMM, batch = (bi%8)>>1 (XCD-aware: vm writes pre-warm the
// L2s that gather will read from). bi==1024: W1->W1T prep for the MLP.
__global__ __launch_bounds__(256, 4)
void proj_kernel(const float* __restrict__ fmap, const float* __restrict__ Wp,
                 const float* __restrict__ W1, unsigned short* __restrict__ vm,
                 float* __restrict__ W1T)
{
    const int bi = blockIdx.x;
    if (bi >= 1024) {
        if (bi == 1024)
            for (int i = threadIdx.x; i < ND*ND; i += 256)
                W1T[(i & 127)*ND + (i >> 7)] = W1[i];   // W1T[d][e] = W1[e][d]
        return;
    }
    const int b    = (bi & 7) >> 1;                 // 2 XCDs per batch
    const int slot = ((bi >> 3) << 1) | (bi & 1);   // [0,256)
    const int p0   = slot * 64;

    const int t    = threadIdx.x;
    const int lane = t & 63;
    const int w    = t >> 6;       // wave -> 16-pixel tile
    const int l15  = lane & 15;
    const int q    = lane >> 4;
    const int cq   = q * 8;        // k-offset within K=32 chunk
    const int p    = p0 + w*16 + l15;

    floatx4 acc[8];
    #pragma unroll
    for (int i = 0; i < 8; ++i) acc[i] = (floatx4)(0.f);

    const float* fbase = fmap + (size_t)b*NC*NHW + p;

    #pragma unroll 2
    for (int c0 = 0; c0 < NC; c0 += 32) {
        // ---- B fragment: B[n=p][k=c0+cq+j], 8 strided dwords -> bf16x8 ----
        const float* bp = fbase + (size_t)(c0 + cq)*NHW;
        float f[8];
        #pragma unroll
        for (int j = 0; j < 8; ++j) f[j] = bp[(size_t)j*NHW];
        union { short8 v; unsigned u[4]; } bc;
        #pragma unroll
        for (int j = 0; j < 4; ++j) bc.u[j] = pk_bf16(f[2*j], f[2*j+1]);
        // ---- A fragments (Wp rows, fp32 -> bf16) + MFMA, d-tiles 0..7 ----
        #pragma unroll
        for (int dt = 0; dt < 8; ++dt) {
            const float* wr = Wp + (size_t)(dt*16 + l15)*NC + c0 + cq;
            float4 g0 = *(const float4*)wr;
            float4 g1 = *(const float4*)(wr + 4);
            union { short8 v; unsigned u[4]; } ac;
            ac.u[0] = pk_bf16(g0.x, g0.y); ac.u[1] = pk_bf16(g0.z, g0.w);
            ac.u[2] = pk_bf16(g1.x, g1.y); ac.u[3] = pk_bf16(g1.z, g1.w);
            acc[dt] = __builtin_amdgcn_mfma_f32_16x16x32_bf16(ac.v, bc.v, acc[dt], 0, 0, 0);
        }
    }
    // ---- epilogue: C row=(q*4+reg)->d, col=l15->p (verified round 2) ----
    #pragma unroll
    for (int dt = 0; dt < 8; ++dt) {
        const int d = dt*16 + q*4;
        floatx4 v = acc[dt];
        uint2 pk = make_uint2(pk_bf16(v[0], v[1]), pk_bf16(v[2], v[3]));
        *(uint2*)&vm[((size_t)(b*NHW + p))*ND + d] = pk;
    }
}

// Kernel 2: fused 4x4 separable gather (== mean of 9 bilinear samples, bf16 vm)
// + 2-layer MLP. 64 points/block, 512 threads (8 thr/point -> 32 waves/CU cap).
// XCD swizzle: batch = (bi%8)>>1 so each batch's 4MB vm is L2-resident on its
// 2 XCDs. Packed float2 math (v_pk_fma_f32) in both phases.
__global__ __launch_bounds__(512, 8)
void gather_mlp(const unsigned short* __restrict__ vm, const float* __restrict__ coords,
                const float* __restrict__ W1T, const float* __restrict__ b1,
                const float* __restrict__ W2, const float* __restrict__ b2,
                float* __restrict__ out)
{
    __shared__ unsigned short feat[64 * 136];  // row stride 272 B
    __shared__ float part[64][17];
    const int t  = threadIdx.x;
    const int bi = blockIdx.x;
    const int b  = (bi & 7) >> 1;
    const int s  = ((bi >> 3) << 1) | (bi & 1);
    const int g0 = b * NT + s * 64;

    // ---- Phase A: gather. 8 threads per point, 16 bf16 channels each. ----
    {
        const int pt = t >> 3;
        const int c8 = t & 7;
        const int g  = g0 + pt;
        const float cx = coords[(size_t)g*2 + 0];
        const float cy = coords[(size_t)g*2 + 1];
        const float ix = cx * (float)(NW - 1);
        const float iy = cy * (float)(NH - 1);
        const float x0f = floorf(ix), y0f = floorf(iy);
        const int x0 = (int)x0f, y0 = (int)y0f;
        const float wx1 = ix - x0f, wy1 = iy - y0f;
        const float wxv[4] = {1.f - wx1, 1.f, 1.f, wx1};
        const float wyv[4] = {1.f - wy1, 1.f, 1.f, wy1};
        floatx2 acc[8];
        #pragma unroll
        for (int k = 0; k < 8; ++k) acc[k] = (floatx2)(0.f);
        const unsigned short* vmb = vm + (size_t)b*NHW*ND + c8*16;
        #pragma unroll
        for (int j = 0; j < 4; ++j) {
            const int Y  = y0 - 1 + j;
            const int Yc = min(max(Y, 0), NH-1);
            const bool vy = (Y >= 0) & (Y < NH);
            #pragma unroll
            for (int i = 0; i < 4; ++i) {
                const int X  = x0 - 1 + i;
                const int Xc = min(max(X, 0), NW-1);
                const bool vx = (X >= 0) & (X < NW);
                const float wgt = (vx & vy) ? wxv[i]*wyv[j] : 0.f;  // zeros pad
                const unsigned* src = (const unsigned*)(vmb + (size_t)(Yc*NW + Xc)*ND);
                uint4 ua = *(const uint4*)src;
                uint4 ub = *(const uint4*)(src + 4);
                const unsigned uu[8] = {ua.x,ua.y,ua.z,ua.w, ub.x,ub.y,ub.z,ub.w};
                const floatx2 w2 = {wgt, wgt};
                #pragma unroll
                for (int k = 0; k < 8; ++k) {
                    floatx2 v;
                    v.x = __uint_as_float(uu[k] << 16);
                    v.y = __uint_as_float(uu[k] & 0xffff0000u);
                    acc[k] += w2 * v;   // v_pk_fma_f32
                }
            }
        }
        const float s9 = 1.f/9.f;
        unsigned pk[8];
        #pragma unroll
        for (int k = 0; k < 8; ++k)
            pk[k] = pk_bf16(acc[k].x*s9, acc[k].y*s9);
        *(uint4*)&feat[pt*136 + c8*16]     = make_uint4(pk[0],pk[1],pk[2],pk[3]);
        *(uint4*)&feat[pt*136 + c8*16 + 8] = make_uint4(pk[4],pk[5],pk[6],pk[7]);
    }
    __syncthreads();

    // ---- Phase B: layer 1 (+layer-2 partials). thread = (point, 16-wide e-block) ----
    {
        const int pt = t & 63;
        const int eb = t >> 6;
        const int e0 = __builtin_amdgcn_readfirstlane(eb * 16);  // wave-uniform -> s_load
        floatx2 acc[8];
        #pragma unroll
        for (int k = 0; k < 8; ++k) acc[k] = *(const floatx2*)&b1[e0 + 2*k];
        #pragma unroll 2
        for (int d = 0; d < ND; d += 8) {
            ushort8 u = *(const ushort8*)&feat[pt*136 + d];
            #pragma unroll
            for (int jj = 0; jj < 8; ++jj) {
                const float fv = bf2f(u[jj]);
                const floatx2 f2 = {fv, fv};
                const float* wrow = W1T + (size_t)(d + jj)*ND + e0;
                #pragma unroll
                for (int k = 0; k < 8; ++k)
                    acc[k] += f2 * (*(const floatx2*)&wrow[2*k]);
            }
        }
        float s0 = 0.f, s1 = 0.f;
        const float* w20 = W2 + e0;
        const float* w21 = W2 + ND + e0;
        #pragma unroll
        for (int k = 0; k < 8; ++k) {
            float h0 = fmaxf(acc[k].x, 0.f);
            float h1 = fmaxf(acc[k].y, 0.f);
            s0 = fmaf(h0, w20[2*k], fmaf(h1, w20[2*k+1], s0));
            s1 = fmaf(h0, w21[2*k], fmaf(h1, w21[2*k+1], s1));
        }
        part[pt][eb*2 + 0] = s0;
        part[pt][eb*2 + 1] = s1;
    }
    __syncthreads();

    // ---- Phase C: reduce 8 e-blocks, tanh, write ----
    if (t < 64) {
        const int g = g0 + t;
        float s0 = 0.f, s1 = 0.f;
        #pragma unroll
        for (int k = 0; k < 8; ++k) { s0 += part[t][2*k]; s1 += part[t][2*k+1]; }
        const float cx = coords[(size_t)g*2 + 0];
        const float cy = coords[(size_t)g*2 + 1];
        const float MD = 0.5f / 512.0f;
        float2 o = make_float2(cx + tanhf(s0 + b2[0]) * MD,
                               cy + tanhf(s1 + b2[1]) * MD);
        *(float2*)&out[(size_t)g*2] = o;
    }
}

extern "C" void kernel_launch(void* const* d_in, const int* in_sizes, int n_in,
                              void* d_out, int out_size, void* d_ws, size_t ws_size,
                              hipStream_t stream)
{
    const float* fmap   = (const float*)d_in[0];
    const float* coords = (const float*)d_in[1];
    const float* Wp     = (const float*)d_in[2];
    const float* W1     = (const float*)d_in[3];
    const float* b1     = (const float*)d_in[4];
    const float* W2     = (const float*)d_in[5];
    const float* b2     = (const float*)d_in[6];
    float* out = (float*)d_out;

    unsigned short* vm = (unsigned short*)d_ws;                 // (B,HW,D) bf16: 16 MB
    float* W1T = (float*)((char*)d_ws + (size_t)NB*NHW*ND*2);   // 128x128 fp32: 64 KB

    proj_kernel<<<dim3(1024 + 8), 256, 0, stream>>>(fmap, Wp, W1, vm, W1T);
    gather_mlp<<<dim3(1024), 512, 0, stream>>>(vm, coords, W1T, b1, W2, b2, out);
}

// Round 5
// 159.523 us; speedup vs baseline: 2.2363x; 1.3018x over previous
//
#include <hip/hip_runtime.h>
#include <cstddef>

#define NB 4
#define NC 256
#define ND 128
#define NH 128
#define NW 128
#define NHW (NH*NW)
#define NT 16384

typedef short   short8  __attribute__((ext_vector_type(8)));
typedef unsigned short ushort8 __attribute__((ext_vector_type(8)));
typedef float   floatx4 __attribute__((ext_vector_type(4)));
typedef float   floatx2 __attribute__((ext_vector_type(2)));

// RNE fp32->bf16 pack of two floats into one dword (low ushort = first arg)
__device__ __forceinline__ unsigned pk_bf16(float a, float b) {
    unsigned ua = __float_as_uint(a);
    unsigned ub = __float_as_uint(b);
    ua += 0x7fffu + ((ua >> 16) & 1u);
    ub += 0x7fffu + ((ub >> 16) & 1u);
    return (ua >> 16) | (ub & 0xffff0000u);
}

__device__ __forceinline__ float bf2f(unsigned short u) {
    return __uint_as_float(((unsigned)u) << 16);
}

// ---- fp8 e4m3 (OCP) helpers: HW cvt on gfx950 ----
__device__ __forceinline__ unsigned fp8x4_from_f32(float v0, float v1, float v2, float v3) {
#if __has_builtin(__builtin_amdgcn_cvt_pk_fp8_f32)
    int r = 0;
    r = __builtin_amdgcn_cvt_pk_fp8_f32(v0, v1, r, false);
    r = __builtin_amdgcn_cvt_pk_fp8_f32(v2, v3, r, true);
    return (unsigned)r;
#else
    auto enc1 = [](float x) -> unsigned {
        unsigned u = __float_as_uint(x);
        unsigned s = (u >> 24) & 0x80u;
        float ax = fabsf(x);
        if (ax < 0.015625f) return s;
        if (ax > 448.f) return s | 0x7Eu;
        u = __float_as_uint(ax);
        u += 0x7ffffu + ((u >> 20) & 1u);        // RNE to 3 mantissa bits
        unsigned e = (u >> 23) - 120u;
        return s | ((e & 15u) << 3) | ((u >> 20) & 7u);
    };
    return enc1(v0) | (enc1(v1) << 8) | (enc1(v2) << 16) | (enc1(v3) << 24);
#endif
}

// hi-word selector must be a compile-time constant for the builtin -> template
template <bool HI>
__device__ __forceinline__ floatx2 fp8x2_to_f32(unsigned w) {
#if __has_builtin(__builtin_amdgcn_cvt_pk_f32_fp8)
    return __builtin_amdgcn_cvt_pk_f32_fp8((int)w, HI);
#else
    auto dec1 = [](unsigned b) -> float {
        unsigned s = (b & 0x80u) << 24;
        unsigned em = b & 0x7Fu;
        if (em == 0) return __uint_as_float(s);
        return __uint_as_float(s | (((em >> 3) + 120u) << 23) | ((em & 7u) << 20));
    };
    unsigned v = HI ? (w >> 16) : w;
    floatx2 r; r.x = dec1(v & 0xFFu); r.y = dec1((v >> 8) & 0xFFu);
    return r;
#endif
}

// Kernel 1: vm[b][p][d] = sum_c fmap[b][c][p] * Wp[d][c], OUTPUT fp8 e4m3 channel-last.
// Wp is staged ONCE per block into LDS as bf16 per-lane A-fragments (64 KB,
// fragment-ordered: ds_read_b128 is 16B/lane contiguous -> conflict-free).
// K-loop per wave per chunk: 8 strided B-dwords + 8 ds_read_b128 + 8 MFMA.
// This removes the 512MB of per-wave Wp re-reads from L2 that bounded round 3.
// 512 threads, 8 waves, 128 px/block; grid 512 (+1 for W1->W1T prep).
// XCD swizzle: batch b = (bi%8)>>1 so vm writes pre-warm the L2s gather reads.
__global__ __launch_bounds__(512, 4)
void proj_kernel(const float* __restrict__ fmap, const float* __restrict__ Wp,
                 const float* __restrict__ W1, unsigned char* __restrict__ vm,
                 float* __restrict__ W1T)
{
    const int bi = blockIdx.x;
    if (bi >= 512) {
        if (bi == 512)
            for (int i = threadIdx.x; i < ND*ND; i += 512)
                W1T[(i & 127)*ND + (i >> 7)] = W1[i];   // W1T[d][e] = W1[e][d]
        return;
    }
    __shared__ unsigned short awp[8*8*64*8];   // [dt][ch][lane][8 bf16] = 64 KB

    const int t    = threadIdx.x;
    const int lane = t & 63;
    const int w    = t >> 6;       // wave id 0..7
    const int l15  = lane & 15;
    const int q    = lane >> 4;
    const int cq   = q * 8;

    // ---- stage Wp -> LDS A-fragments: thread covers (dt=w, ch=0..7, its lane) ----
    {
        const int dt = w;
        const float* wr0 = Wp + (size_t)(dt*16 + l15)*NC + cq;
        #pragma unroll
        for (int ch = 0; ch < 8; ++ch) {
            float4 g0 = *(const float4*)(wr0 + ch*32);
            float4 g1 = *(const float4*)(wr0 + ch*32 + 4);
            uint4 pk = make_uint4(pk_bf16(g0.x,g0.y), pk_bf16(g0.z,g0.w),
                                  pk_bf16(g1.x,g1.y), pk_bf16(g1.z,g1.w));
            *(uint4*)&awp[((dt*8 + ch)*64 + lane)*8] = pk;
        }
    }
    __syncthreads();

    const int b    = (bi & 7) >> 1;                 // 2 XCDs per batch
    const int slot = ((bi >> 3) << 1) | (bi & 1);   // [0,128)
    const int p    = slot*128 + w*16 + l15;

    floatx4 acc[8];
    #pragma unroll
    for (int i = 0; i < 8; ++i) acc[i] = (floatx4)(0.f);

    const float* fbase = fmap + (size_t)b*NC*NHW + p;

    #pragma unroll 2
    for (int c0 = 0; c0 < 8; ++c0) {
        // ---- B fragment: B[n=p][k=c0*32+cq+j], 8 strided dwords -> bf16x8 ----
        const float* bp = fbase + (size_t)(c0*32 + cq)*NHW;
        float f[8];
        #pragma unroll
        for (int j = 0; j < 8; ++j) f[j] = bp[(size_t)j*NHW];
        union { short8 v; unsigned u[4]; } bc;
        #pragma unroll
        for (int j = 0; j < 4; ++j) bc.u[j] = pk_bf16(f[2*j], f[2*j+1]);
        // ---- A from LDS + MFMA, d-tiles 0..7 ----
        #pragma unroll
        for (int dt = 0; dt < 8; ++dt) {
            short8 afr = *(const short8*)&awp[((dt*8 + c0)*64 + lane)*8];
            acc[dt] = __builtin_amdgcn_mfma_f32_16x16x32_bf16(afr, bc.v, acc[dt], 0, 0, 0);
        }
    }
    // ---- epilogue: C row=(q*4+reg)->d, col=l15->p; pack 4 d to fp8 dword ----
    unsigned char* vrow = vm + ((size_t)(b*NHW + p))*ND;
    #pragma unroll
    for (int dt = 0; dt < 8; ++dt) {
        floatx4 v = acc[dt];
        *(unsigned*)&vrow[dt*16 + q*4] = fp8x4_from_f32(v[0], v[1], v[2], v[3]);
    }
}

// Kernel 2: fused 4x4 separable gather (== mean of 9 bilinear samples, fp8 vm)
// + 2-layer MLP. 64 points/block, 512 threads (8 thr/pt, 16 fp8 ch each: ONE
// uint4 load per pixel). XCD swizzle: batch's 2MB vm L2-resident on its 2 XCDs.
__global__ __launch_bounds__(512, 8)
void gather_mlp(const unsigned char* __restrict__ vm, const float* __restrict__ coords,
                const float* __restrict__ W1T, const float* __restrict__ b1,
                const float* __restrict__ W2, const float* __restrict__ b2,
                float* __restrict__ out)
{
    __shared__ unsigned short feat[64 * 136];  // row stride 272 B
    __shared__ float part[64][17];
    const int t  = threadIdx.x;
    const int bi = blockIdx.x;
    const int b  = (bi & 7) >> 1;
    const int s  = ((bi >> 3) << 1) | (bi & 1);
    const int g0 = b * NT + s * 64;

    // ---- Phase A: gather. 8 threads per point, 16 fp8 channels each. ----
    {
        const int pt = t >> 3;
        const int c8 = t & 7;
        const int g  = g0 + pt;
        const float cx = coords[(size_t)g*2 + 0];
        const float cy = coords[(size_t)g*2 + 1];
        const float ix = cx * (float)(NW - 1);
        const float iy = cy * (float)(NH - 1);
        const float x0f = floorf(ix), y0f = floorf(iy);
        const int x0 = (int)x0f, y0 = (int)y0f;
        const float wx1 = ix - x0f, wy1 = iy - y0f;
        const float wxv[4] = {1.f - wx1, 1.f, 1.f, wx1};
        const float wyv[4] = {1.f - wy1, 1.f, 1.f, wy1};
        floatx2 acc[8];
        #pragma unroll
        for (int k = 0; k < 8; ++k) acc[k] = (floatx2)(0.f);
        const unsigned char* vmb = vm + (size_t)b*NHW*ND + c8*16;
        #pragma unroll
        for (int j = 0; j < 4; ++j) {
            const int Y  = y0 - 1 + j;
            const int Yc = min(max(Y, 0), NH-1);
            const bool vy = (Y >= 0) & (Y < NH);
            #pragma unroll
            for (int i = 0; i < 4; ++i) {
                const int X  = x0 - 1 + i;
                const int Xc = min(max(X, 0), NW-1);
                const bool vx = (X >= 0) & (X < NW);
                const float wgt = (vx & vy) ? wxv[i]*wyv[j] : 0.f;  // zeros pad
                uint4 u = *(const uint4*)(vmb + (size_t)(Yc*NW + Xc)*ND);
                const floatx2 w2 = {wgt, wgt};
                acc[0] += w2 * fp8x2_to_f32<false>(u.x);
                acc[1] += w2 * fp8x2_to_f32<true >(u.x);
                acc[2] += w2 * fp8x2_to_f32<false>(u.y);
                acc[3] += w2 * fp8x2_to_f32<true >(u.y);
                acc[4] += w2 * fp8x2_to_f32<false>(u.z);
                acc[5] += w2 * fp8x2_to_f32<true >(u.z);
                acc[6] += w2 * fp8x2_to_f32<false>(u.w);
                acc[7] += w2 * fp8x2_to_f32<true >(u.w);
            }
        }
        const float s9 = 1.f/9.f;
        unsigned pk[8];
        #pragma unroll
        for (int k = 0; k < 8; ++k)
            pk[k] = pk_bf16(acc[k].x*s9, acc[k].y*s9);
        *(uint4*)&feat[pt*136 + c8*16]     = make_uint4(pk[0],pk[1],pk[2],pk[3]);
        *(uint4*)&feat[pt*136 + c8*16 + 8] = make_uint4(pk[4],pk[5],pk[6],pk[7]);
    }
    __syncthreads();

    // ---- Phase B: layer 1 (+layer-2 partials). thread = (point, 16-wide e-block) ----
    {
        const int pt = t & 63;
        const int eb = t >> 6;
        const int e0 = __builtin_amdgcn_readfirstlane(eb * 16);  // wave-uniform -> s_load
        floatx2 acc[8];
        #pragma unroll
        for (int k = 0; k < 8; ++k) acc[k] = *(const floatx2*)&b1[e0 + 2*k];
        #pragma unroll 2
        for (int d = 0; d < ND; d += 8) {
            ushort8 u = *(const ushort8*)&feat[pt*136 + d];
            #pragma unroll
            for (int jj = 0; jj < 8; ++jj) {
                const float fv = bf2f(u[jj]);
                const floatx2 f2 = {fv, fv};
                const float* wrow = W1T + (size_t)(d + jj)*ND + e0;
                #pragma unroll
                for (int k = 0; k < 8; ++k)
                    acc[k] += f2 * (*(const floatx2*)&wrow[2*k]);
            }
        }
        float s0 = 0.f, s1 = 0.f;
        const float* w20 = W2 + e0;
        const float* w21 = W2 + ND + e0;
        #pragma unroll
        for (int k = 0; k < 8; ++k) {
            float h0 = fmaxf(acc[k].x, 0.f);
            float h1 = fmaxf(acc[k].y, 0.f);
            s0 = fmaf(h0, w20[2*k], fmaf(h1, w20[2*k+1], s0));
            s1 = fmaf(h0, w21[2*k], fmaf(h1, w21[2*k+1], s1));
        }
        part[pt][eb*2 + 0] = s0;
        part[pt][eb*2 + 1] = s1;
    }
    __syncthreads();

    // ---- Phase C: reduce 8 e-blocks, tanh, write ----
    if (t < 64) {
        const int g = g0 + t;
        float s0 = 0.f, s1 = 0.f;
        #pragma unroll
        for (int k = 0; k < 8; ++k) { s0 += part[t][2*k]; s1 += part[t][2*k+1]; }
        const float cx = coords[(size_t)g*2 + 0];
        const float cy = coords[(size_t)g*2 + 1];
        const float MD = 0.5f / 512.0f;
        float2 o = make_float2(cx + tanhf(s0 + b2[0]) * MD,
                               cy + tanhf(s1 + b2[1]) * MD);
        *(float2*)&out[(size_t)g*2] = o;
    }
}

extern "C" void kernel_launch(void* const* d_in, const int* in_sizes, int n_in,
                              void* d_out, int out_size, void* d_ws, size_t ws_size,
                              hipStream_t stream)
{
    const float* fmap   = (const float*)d_in[0];
    const float* coords = (const float*)d_in[1];
    const float* Wp     = (const float*)d_in[2];
    const float* W1     = (const float*)d_in[3];
    const float* b1     = (const float*)d_in[4];
    const float* W2     = (const float*)d_in[5];
    const float* b2     = (const float*)d_in[6];
    float* out = (float*)d_out;

    unsigned char* vm = (unsigned char*)d_ws;                   // (B,HW,D) fp8: 8 MB
    float* W1T = (float*)((char*)d_ws + (size_t)NB*NHW*ND);     // 128x128 fp32: 64 KB

    proj_kernel<<<dim3(512 + 1), 512, 0, stream>>>(fmap, Wp, W1, vm, W1T);
    gather_mlp<<<dim3(1024), 512, 0, stream>>>(vm, coords, W1T, b1, W2, b2, out);
}